// Round 13
// baseline (120.228 us; speedup 1.0000x reference)
//
#include <hip/hip_runtime.h>
#include <hip/hip_fp16.h>

// GAE reverse affine scan + standardize — R6 structure + nontemporal streaming.
// adv_k = delta_k + c_k*adv_{k+1}; delta_k = r_k + g*V_{k+1}*nd_k - V_k; c_k = g*l*nd_k.
// Affine f(x)=D+C*x; compose(left,right) = (Dl+Cl*Dr, Cl*Cr).
// Wave owns a 1024-elem chunk (2 tiles of 512; lane owns 8 contiguous elems).
// k_desc: nt-load r,v,dn (read exactly once -> bypass cache churn); persist fp16 delta
//         (32 MB) + done bitmask (2 MB) + per-chunk desc + 5-moment tuple.
// k_scan: single block, shuffle-based scan of 16384 descs -> carries + mean/std.
// k_apply: read dh+mask (L2/L3-hot), rescan, apply carry, normalize, nt-store out.

#define GAMMA_F 0.99f
#define GL_F 0.9405f            // 0.99*0.95
#define EPS_F 1e-8f

constexpr int NT = 256;          // 4 waves per block
constexpr int PL = 8;            // elems per lane
constexpr int TILE = 512;        // elems per wave-tile (64*8)
constexpr int CHUNK = 2 * TILE;  // 1024 elems per wave-chunk
constexpr int K2T = 1024;        // k_scan threads

typedef float f4n __attribute__((ext_vector_type(4)));
typedef int   i4n __attribute__((ext_vector_type(4)));

__device__ __forceinline__ float4 nt_load_f4(const float* p) {
    f4n v = __builtin_nontemporal_load((const f4n*)p);
    return make_float4(v.x, v.y, v.z, v.w);
}
__device__ __forceinline__ int4 nt_load_i4(const int* p) {
    i4n v = __builtin_nontemporal_load((const i4n*)p);
    return make_int4(v.x, v.y, v.z, v.w);
}
__device__ __forceinline__ void nt_store4(float* p, float a, float b, float c, float d) {
    f4n v; v.x = a; v.y = b; v.z = c; v.w = d;
    __builtin_nontemporal_store(v, (f4n*)p);
}

union H8 { __half h[8]; float4 f4; };

// Suffix scan of 8 per-lane affines across the wave.
// sD,sC = A_lane∘...∘A_63 ; S1D,S1C = exclusive (identity at lane 63).
__device__ __forceinline__ void scan8(const float* d, const float* c, int lane,
                                      float& sD, float& sC, float& S1D, float& S1C) {
    float D = 0.f, C = 1.f;
#pragma unroll
    for (int i = 7; i >= 0; --i) { D = d[i] + c[i] * D; C *= c[i]; }
#pragma unroll
    for (int off = 1; off < 64; off <<= 1) {
        float tD = __shfl_down(D, off);
        float tC = __shfl_down(C, off);
        if (lane + off < 64) { D = D + C * tD; C = C * tC; }
    }
    sD = D; sC = C;
    S1D = __shfl_down(D, 1); S1C = __shfl_down(C, 1);
    if (lane == 63) { S1D = 0.f; S1C = 1.f; }
}

// delta/cont for one 512-elem tile from raw inputs, then scan.
__device__ __forceinline__ void tile_scan(const float4& r0, const float4& r1,
                                          const float4& v0, const float4& v1,
                                          const float* nd, float vn63, int lane,
                                          float* d, float* c,
                                          float& sD, float& sC, float& S1D, float& S1C) {
    float vnext = __shfl_down(v0.x, 1);
    if (lane == 63) vnext = vn63;
    float va[9] = {v0.x, v0.y, v0.z, v0.w, v1.x, v1.y, v1.z, v1.w, vnext};
    float rf[8] = {r0.x, r0.y, r0.z, r0.w, r1.x, r1.y, r1.z, r1.w};
#pragma unroll
    for (int i = 0; i < 8; ++i) {
        d[i] = rf[i] + GAMMA_F * va[i + 1] * nd[i] - va[i];
        c[i] = GL_F * nd[i];
    }
    scan8(d, c, lane, sD, sC, S1D, S1C);
}

// Per-lane tile-local moments (entry 0 at tile right edge): {Σloc, ΣP, Σloc², Σloc·P, ΣP²}.
__device__ __forceinline__ void lane_moms(const float* d, const float* c,
                                          float S1D, float S1C, float* mm) {
    float x = S1D, P = S1C;
    float A = 0.f, Pp = 0.f, L2 = 0.f, LP = 0.f, P2 = 0.f;
#pragma unroll
    for (int i = 7; i >= 0; --i) {
        x = d[i] + c[i] * x;
        P *= c[i];
        A += x; Pp += P; L2 += x * x; LP += x * P; P2 += P * P;
    }
    mm[0] = A; mm[1] = Pp; mm[2] = L2; mm[3] = LP; mm[4] = P2;
}

// Pass 1: per-chunk desc + moments + done-mask + persisted fp16 delta. NT input loads.
__global__ __launch_bounds__(NT) void k_desc(const float* __restrict__ r,
                                             const float* __restrict__ v,
                                             const int* __restrict__ dn,
                                             float2* __restrict__ desc,
                                             float4* __restrict__ mom4,
                                             float* __restrict__ mom1,
                                             unsigned long long* __restrict__ dmask,
                                             __half* __restrict__ dh) {
    const int tid = threadIdx.x, lane = tid & 63, wv = tid >> 6;
    const int ch = blockIdx.x * 4 + wv;
    const int base = ch * CHUNK;
    const int o0 = base + lane * PL, o1 = base + TILE + lane * PL;

    float4 r00 = nt_load_f4(r + o0), r01 = nt_load_f4(r + o0 + 4);
    float4 v00 = nt_load_f4(v + o0), v01 = nt_load_f4(v + o0 + 4);
    int4   a00 = nt_load_i4(dn + o0), a01 = nt_load_i4(dn + o0 + 4);
    float4 r10 = nt_load_f4(r + o1), r11 = nt_load_f4(r + o1 + 4);
    float4 v10 = nt_load_f4(v + o1), v11 = nt_load_f4(v + o1 + 4);
    int4   a10 = nt_load_i4(dn + o1), a11 = nt_load_i4(dn + o1 + 4);

    float vn63_t1 = (lane == 63) ? v[base + CHUNK] : 0.f;   // v has T+1 elems
    float vn63_t0 = __shfl(v10.x, 0);

    int di0[8] = {a00.x, a00.y, a00.z, a00.w, a01.x, a01.y, a01.z, a01.w};
    int di1[8] = {a10.x, a10.y, a10.z, a10.w, a11.x, a11.y, a11.z, a11.w};
    float nd0[8], nd1[8];
    unsigned long long m0[8], m1[8];
#pragma unroll
    for (int i = 0; i < 8; ++i) {
        nd0[i] = 1.f - (float)di0[i]; m0[i] = __ballot(di0[i] != 0);
        nd1[i] = 1.f - (float)di1[i]; m1[i] = __ballot(di1[i] != 0);
    }

    float d1[8], c1[8], sD1, sC1, S1D1, S1C1;
    tile_scan(r10, r11, v10, v11, nd1, vn63_t1, lane, d1, c1, sD1, sC1, S1D1, S1C1);
    const float T1D = __shfl(sD1, 0), T1C = __shfl(sC1, 0);
    float d0[8], c0[8], sD0, sC0, S1D0, S1C0;
    tile_scan(r00, r01, v00, v01, nd0, vn63_t0, lane, d0, c0, sD0, sC0, S1D0, S1C0);
    const float T0D = __shfl(sD0, 0), T0C = __shfl(sC0, 0);

    // persist fp16 delta (coalesced 16B/lane)
    H8 u0, u1;
#pragma unroll
    for (int i = 0; i < 8; ++i) { u0.h[i] = __float2half(d0[i]); u1.h[i] = __float2half(d1[i]); }
    *(float4*)(dh + o0) = u0.f4;
    *(float4*)(dh + o1) = u1.f4;

    float mm1[5], mm0[5];
    lane_moms(d1, c1, S1D1, S1C1, mm1);
    lane_moms(d0, c0, S1D0, S1C0, mm0);
    const float e = T1D, f = T1C;   // lift tile0 moments through tile1's affine
    float gA  = mm1[0] + mm0[0] + e * mm0[1];
    float gP  = mm1[1] + f * mm0[1];
    float gL2 = mm1[2] + mm0[2] + 2.f * e * mm0[3] + e * e * mm0[4];
    float gLP = mm1[3] + f * (mm0[3] + e * mm0[4]);
    float gP2 = mm1[4] + f * f * mm0[4];
#pragma unroll
    for (int off = 32; off > 0; off >>= 1) {
        gA  += __shfl_down(gA,  off);
        gP  += __shfl_down(gP,  off);
        gL2 += __shfl_down(gL2, off);
        gLP += __shfl_down(gLP, off);
        gP2 += __shfl_down(gP2, off);
    }
    if (lane == 0) {
        desc[ch] = make_float2(T0D + T0C * T1D, T0C * T1C);
        mom4[ch] = make_float4(gA, gP, gL2, gLP);
        mom1[ch] = gP2;
        unsigned long long* mp = dmask + (size_t)ch * 16;
#pragma unroll
        for (int i = 0; i < 8; ++i) { mp[i] = m0[i]; mp[8 + i] = m1[i]; }
    }
}

// Pass 2: scan 16384 chunk descs -> carries; combine moments -> mean, 1/(std+eps).
// Shuffle-based, 2 barriers total. (R9-proven.)
__global__ __launch_bounds__(K2T) void k_scan(const float2* __restrict__ desc,
                                              const float4* __restrict__ mom4,
                                              const float* __restrict__ mom1,
                                              float* __restrict__ carry,
                                              float2* __restrict__ meanstd,
                                              int nchunk, long long T) {
    const int t = threadIdx.x, lane = t & 63, wv = t >> 6;   // 16 waves
    const int per = nchunk / K2T;   // 16
    const int s = t * per;
    float D = 0.f, C = 1.f;
    for (int i = per - 1; i >= 0; --i) { float2 a = desc[s + i]; D = a.x + a.y * D; C *= a.y; }
    float sD = D, sC = C;
#pragma unroll
    for (int off = 1; off < 64; off <<= 1) {
        float tD = __shfl_down(sD, off), tC = __shfl_down(sC, off);
        if (lane + off < 64) { sD = sD + sC * tD; sC = sC * tC; }
    }
    __shared__ float2 waff[16];
    if (lane == 0) waff[wv] = make_float2(sD, sC);
    __syncthreads();
    float xw = 0.f;                              // value entering this wave from the right
    for (int w = 15; w > wv; --w) xw = waff[w].x + waff[w].y * xw;
    float S1D = __shfl_down(sD, 1), S1C = __shfl_down(sC, 1);
    if (lane == 63) { S1D = 0.f; S1C = 1.f; }
    float x = S1D + S1C * xw;                    // value entering this thread's range
    double gS = 0.0, gQ = 0.0;
    for (int i = per - 1; i >= 0; --i) {
        const int cix = s + i;
        carry[cix] = x;
        float4 m = mom4[cix];
        float p2 = mom1[cix];
        gS += (double)(m.x + x * m.y);
        gQ += (double)(m.z + 2.f * x * m.w + x * x * p2);
        float2 a = desc[cix];
        x = a.x + a.y * x;
    }
#pragma unroll
    for (int off = 32; off > 0; off >>= 1) {
        gS += __shfl_down(gS, off);
        gQ += __shfl_down(gQ, off);
    }
    __shared__ double Sa[16], Sb[16];
    if (lane == 0) { Sa[wv] = gS; Sb[wv] = gQ; }
    __syncthreads();
    if (t == 0) {
        double S = 0.0, Q = 0.0;
        for (int w = 0; w < 16; ++w) { S += Sa[w]; Q += Sb[w]; }
        double mean = S / (double)T;
        double var = Q / (double)T - mean * mean;
        double sd = sqrt(var > 0.0 ? var : 0.0);
        meanstd[0] = make_float2((float)mean, (float)(1.0 / (sd + (double)EPS_F)));
    }
}

// Pass 3: read fp16 delta + mask (cache-hot), rescan, apply carry, normalize, nt-store out.
__global__ __launch_bounds__(NT) void k_apply(const __half* __restrict__ dh,
                                              const unsigned long long* __restrict__ dmask,
                                              const float* __restrict__ carry,
                                              const float2* __restrict__ meanstd,
                                              float* __restrict__ out) {
    const int tid = threadIdx.x, lane = tid & 63, wv = tid >> 6;
    const int ch = blockIdx.x * 4 + wv;
    const int base = ch * CHUNK;
    const int o0 = base + lane * PL, o1 = base + TILE + lane * PL;

    float d0[8], d1[8];
    H8 u0, u1;
    u0.f4 = *(const float4*)(dh + o0);
    u1.f4 = *(const float4*)(dh + o1);
#pragma unroll
    for (int i = 0; i < 8; ++i) { d0[i] = __half2float(u0.h[i]); d1[i] = __half2float(u1.h[i]); }

    const unsigned long long* mp = dmask + (size_t)ch * 16;
    float c0[8], c1[8];
#pragma unroll
    for (int i = 0; i < 8; ++i) {
        c0[i] = GL_F * (1.f - (float)((mp[i] >> lane) & 1ull));
        c1[i] = GL_F * (1.f - (float)((mp[8 + i] >> lane) & 1ull));
    }
    const float2 ms = meanstd[0];
    const float cy = carry[ch];

    float sD1, sC1, S1D1, S1C1;
    scan8(d1, c1, lane, sD1, sC1, S1D1, S1C1);
    const float T1D = __shfl(sD1, 0), T1C = __shfl(sC1, 0);
    float sD0, sC0, S1D0, S1C0;
    scan8(d0, c0, lane, sD0, sC0, S1D0, S1C0);

    float o[8];
    float x = S1D1 + S1C1 * cy;                   // tile1: entry = cy at chunk right edge
#pragma unroll
    for (int i = 7; i >= 0; --i) { x = d1[i] + c1[i] * x; o[i] = (x - ms.x) * ms.y; }
    nt_store4(out + o1,     o[0], o[1], o[2], o[3]);
    nt_store4(out + o1 + 4, o[4], o[5], o[6], o[7]);
    const float x0e = T1D + T1C * cy;             // tile0: entry = A_tile1(cy)
    x = S1D0 + S1C0 * x0e;
#pragma unroll
    for (int i = 7; i >= 0; --i) { x = d0[i] + c0[i] * x; o[i] = (x - ms.x) * ms.y; }
    nt_store4(out + o0,     o[0], o[1], o[2], o[3]);
    nt_store4(out + o0 + 4, o[4], o[5], o[6], o[7]);
}

extern "C" void kernel_launch(void* const* d_in, const int* in_sizes, int n_in,
                              void* d_out, int out_size, void* d_ws, size_t ws_size,
                              hipStream_t stream) {
    const float* rewards = (const float*)d_in[0];
    const float* v_pred  = (const float*)d_in[1];
    const int*   dones   = (const int*)d_in[2];
    float* out = (float*)d_out;
    const long long T = in_sizes[0];          // 16777216
    const int nchunk = (int)(T / CHUNK);      // 16384

    // workspace layout (ws_size >= 36 MB proven in R6)
    char* ws = (char*)d_ws;
    float4* mom4 = (float4*)ws;                                       // 256 KB
    float2* desc = (float2*)(ws + (size_t)nchunk * 16);               // 128 KB
    float*  mom1 = (float*)(ws + (size_t)nchunk * 24);                // 64 KB
    float*  carry = (float*)(ws + (size_t)nchunk * 28);               // 64 KB
    float2* meanstd = (float2*)(ws + (size_t)nchunk * 32);            // 16 B
    unsigned long long* dmask =
        (unsigned long long*)(ws + (size_t)nchunk * 32 + 16);         // 2 MB
    __half* dh = (__half*)(ws + 4ull * 1024 * 1024);                  // 32 MB @ 4 MB

    hipLaunchKernelGGL(k_desc, dim3(nchunk / 4), dim3(NT), 0, stream,
                       rewards, v_pred, dones, desc, mom4, mom1, dmask, dh);
    hipLaunchKernelGGL(k_scan, dim3(1), dim3(K2T), 0, stream,
                       desc, mom4, mom1, carry, meanstd, nchunk, T);
    hipLaunchKernelGGL(k_apply, dim3(nchunk / 4), dim3(NT), 0, stream,
                       dh, dmask, carry, meanstd, out);
}

// Round 14
// 117.738 us; speedup vs baseline: 1.0211x; 1.0211x over previous
//
#include <hip/hip_runtime.h>
#include <hip/hip_fp16.h>

// GAE reverse affine scan + standardize — nt-load inputs, regular stores elsewhere.
// adv_k = delta_k + c_k*adv_{k+1}; delta_k = r_k + g*V_{k+1}*nd_k - V_k; c_k = g*l*nd_k.
// Affine f(x)=D+C*x; compose(left,right) = (Dl+Cl*Dr, Cl*Cr).
// Wave owns a 1024-elem chunk (2 tiles of 512; lane owns 8 contiguous elems).
// k_desc: NT-load r,v,dn (use-once streams -> bypass cache churn; R13-proven −26 µs);
//         persist fp16 delta (32 MB) + done bitmask (2 MB) + desc + 5-moment tuple.
// k_scan: single block, shuffle-based scan of 16384 descs -> carries + mean/std.
// k_apply: read dh+mask (cache-hot), rescan, apply carry, normalize, REGULAR out stores
//          (R6-proven; nt out-stores cost ~+40 µs in R13).

#define GAMMA_F 0.99f
#define GL_F 0.9405f            // 0.99*0.95
#define EPS_F 1e-8f

constexpr int NT = 256;          // 4 waves per block
constexpr int PL = 8;            // elems per lane
constexpr int TILE = 512;        // elems per wave-tile (64*8)
constexpr int CHUNK = 2 * TILE;  // 1024 elems per wave-chunk
constexpr int K2T = 1024;        // k_scan threads

typedef float f4n __attribute__((ext_vector_type(4)));
typedef int   i4n __attribute__((ext_vector_type(4)));

__device__ __forceinline__ float4 nt_load_f4(const float* p) {
    f4n v = __builtin_nontemporal_load((const f4n*)p);
    return make_float4(v.x, v.y, v.z, v.w);
}
__device__ __forceinline__ int4 nt_load_i4(const int* p) {
    i4n v = __builtin_nontemporal_load((const i4n*)p);
    return make_int4(v.x, v.y, v.z, v.w);
}

union H8 { __half h[8]; float4 f4; };

// Suffix scan of 8 per-lane affines across the wave.
// sD,sC = A_lane∘...∘A_63 ; S1D,S1C = exclusive (identity at lane 63).
__device__ __forceinline__ void scan8(const float* d, const float* c, int lane,
                                      float& sD, float& sC, float& S1D, float& S1C) {
    float D = 0.f, C = 1.f;
#pragma unroll
    for (int i = 7; i >= 0; --i) { D = d[i] + c[i] * D; C *= c[i]; }
#pragma unroll
    for (int off = 1; off < 64; off <<= 1) {
        float tD = __shfl_down(D, off);
        float tC = __shfl_down(C, off);
        if (lane + off < 64) { D = D + C * tD; C = C * tC; }
    }
    sD = D; sC = C;
    S1D = __shfl_down(D, 1); S1C = __shfl_down(C, 1);
    if (lane == 63) { S1D = 0.f; S1C = 1.f; }
}

// delta/cont for one 512-elem tile from raw inputs, then scan.
__device__ __forceinline__ void tile_scan(const float4& r0, const float4& r1,
                                          const float4& v0, const float4& v1,
                                          const float* nd, float vn63, int lane,
                                          float* d, float* c,
                                          float& sD, float& sC, float& S1D, float& S1C) {
    float vnext = __shfl_down(v0.x, 1);
    if (lane == 63) vnext = vn63;
    float va[9] = {v0.x, v0.y, v0.z, v0.w, v1.x, v1.y, v1.z, v1.w, vnext};
    float rf[8] = {r0.x, r0.y, r0.z, r0.w, r1.x, r1.y, r1.z, r1.w};
#pragma unroll
    for (int i = 0; i < 8; ++i) {
        d[i] = rf[i] + GAMMA_F * va[i + 1] * nd[i] - va[i];
        c[i] = GL_F * nd[i];
    }
    scan8(d, c, lane, sD, sC, S1D, S1C);
}

// Per-lane tile-local moments (entry 0 at tile right edge): {Σloc, ΣP, Σloc², Σloc·P, ΣP²}.
__device__ __forceinline__ void lane_moms(const float* d, const float* c,
                                          float S1D, float S1C, float* mm) {
    float x = S1D, P = S1C;
    float A = 0.f, Pp = 0.f, L2 = 0.f, LP = 0.f, P2 = 0.f;
#pragma unroll
    for (int i = 7; i >= 0; --i) {
        x = d[i] + c[i] * x;
        P *= c[i];
        A += x; Pp += P; L2 += x * x; LP += x * P; P2 += P * P;
    }
    mm[0] = A; mm[1] = Pp; mm[2] = L2; mm[3] = LP; mm[4] = P2;
}

// Pass 1: per-chunk desc + moments + done-mask + persisted fp16 delta. NT input loads.
__global__ __launch_bounds__(NT) void k_desc(const float* __restrict__ r,
                                             const float* __restrict__ v,
                                             const int* __restrict__ dn,
                                             float2* __restrict__ desc,
                                             float4* __restrict__ mom4,
                                             float* __restrict__ mom1,
                                             unsigned long long* __restrict__ dmask,
                                             __half* __restrict__ dh) {
    const int tid = threadIdx.x, lane = tid & 63, wv = tid >> 6;
    const int ch = blockIdx.x * 4 + wv;
    const int base = ch * CHUNK;
    const int o0 = base + lane * PL, o1 = base + TILE + lane * PL;

    float4 r00 = nt_load_f4(r + o0), r01 = nt_load_f4(r + o0 + 4);
    float4 v00 = nt_load_f4(v + o0), v01 = nt_load_f4(v + o0 + 4);
    int4   a00 = nt_load_i4(dn + o0), a01 = nt_load_i4(dn + o0 + 4);
    float4 r10 = nt_load_f4(r + o1), r11 = nt_load_f4(r + o1 + 4);
    float4 v10 = nt_load_f4(v + o1), v11 = nt_load_f4(v + o1 + 4);
    int4   a10 = nt_load_i4(dn + o1), a11 = nt_load_i4(dn + o1 + 4);

    float vn63_t1 = (lane == 63) ? v[base + CHUNK] : 0.f;   // v has T+1 elems
    float vn63_t0 = __shfl(v10.x, 0);

    int di0[8] = {a00.x, a00.y, a00.z, a00.w, a01.x, a01.y, a01.z, a01.w};
    int di1[8] = {a10.x, a10.y, a10.z, a10.w, a11.x, a11.y, a11.z, a11.w};
    float nd0[8], nd1[8];
    unsigned long long m0[8], m1[8];
#pragma unroll
    for (int i = 0; i < 8; ++i) {
        nd0[i] = 1.f - (float)di0[i]; m0[i] = __ballot(di0[i] != 0);
        nd1[i] = 1.f - (float)di1[i]; m1[i] = __ballot(di1[i] != 0);
    }

    float d1[8], c1[8], sD1, sC1, S1D1, S1C1;
    tile_scan(r10, r11, v10, v11, nd1, vn63_t1, lane, d1, c1, sD1, sC1, S1D1, S1C1);
    const float T1D = __shfl(sD1, 0), T1C = __shfl(sC1, 0);
    float d0[8], c0[8], sD0, sC0, S1D0, S1C0;
    tile_scan(r00, r01, v00, v01, nd0, vn63_t0, lane, d0, c0, sD0, sC0, S1D0, S1C0);
    const float T0D = __shfl(sD0, 0), T0C = __shfl(sC0, 0);

    // persist fp16 delta (coalesced 16B/lane, regular stores -> cache-resident for k_apply)
    H8 u0, u1;
#pragma unroll
    for (int i = 0; i < 8; ++i) { u0.h[i] = __float2half(d0[i]); u1.h[i] = __float2half(d1[i]); }
    *(float4*)(dh + o0) = u0.f4;
    *(float4*)(dh + o1) = u1.f4;

    float mm1[5], mm0[5];
    lane_moms(d1, c1, S1D1, S1C1, mm1);
    lane_moms(d0, c0, S1D0, S1C0, mm0);
    const float e = T1D, f = T1C;   // lift tile0 moments through tile1's affine
    float gA  = mm1[0] + mm0[0] + e * mm0[1];
    float gP  = mm1[1] + f * mm0[1];
    float gL2 = mm1[2] + mm0[2] + 2.f * e * mm0[3] + e * e * mm0[4];
    float gLP = mm1[3] + f * (mm0[3] + e * mm0[4]);
    float gP2 = mm1[4] + f * f * mm0[4];
#pragma unroll
    for (int off = 32; off > 0; off >>= 1) {
        gA  += __shfl_down(gA,  off);
        gP  += __shfl_down(gP,  off);
        gL2 += __shfl_down(gL2, off);
        gLP += __shfl_down(gLP, off);
        gP2 += __shfl_down(gP2, off);
    }
    if (lane == 0) {
        desc[ch] = make_float2(T0D + T0C * T1D, T0C * T1C);
        mom4[ch] = make_float4(gA, gP, gL2, gLP);
        mom1[ch] = gP2;
        unsigned long long* mp = dmask + (size_t)ch * 16;
#pragma unroll
        for (int i = 0; i < 8; ++i) { mp[i] = m0[i]; mp[8 + i] = m1[i]; }
    }
}

// Pass 2: scan 16384 chunk descs -> carries; combine moments -> mean, 1/(std+eps).
// Shuffle-based, 2 barriers total. (R9-proven.)
__global__ __launch_bounds__(K2T) void k_scan(const float2* __restrict__ desc,
                                              const float4* __restrict__ mom4,
                                              const float* __restrict__ mom1,
                                              float* __restrict__ carry,
                                              float2* __restrict__ meanstd,
                                              int nchunk, long long T) {
    const int t = threadIdx.x, lane = t & 63, wv = t >> 6;   // 16 waves
    const int per = nchunk / K2T;   // 16
    const int s = t * per;
    float D = 0.f, C = 1.f;
    for (int i = per - 1; i >= 0; --i) { float2 a = desc[s + i]; D = a.x + a.y * D; C *= a.y; }
    float sD = D, sC = C;
#pragma unroll
    for (int off = 1; off < 64; off <<= 1) {
        float tD = __shfl_down(sD, off), tC = __shfl_down(sC, off);
        if (lane + off < 64) { sD = sD + sC * tD; sC = sC * tC; }
    }
    __shared__ float2 waff[16];
    if (lane == 0) waff[wv] = make_float2(sD, sC);
    __syncthreads();
    float xw = 0.f;                              // value entering this wave from the right
    for (int w = 15; w > wv; --w) xw = waff[w].x + waff[w].y * xw;
    float S1D = __shfl_down(sD, 1), S1C = __shfl_down(sC, 1);
    if (lane == 63) { S1D = 0.f; S1C = 1.f; }
    float x = S1D + S1C * xw;                    // value entering this thread's range
    double gS = 0.0, gQ = 0.0;
    for (int i = per - 1; i >= 0; --i) {
        const int cix = s + i;
        carry[cix] = x;
        float4 m = mom4[cix];
        float p2 = mom1[cix];
        gS += (double)(m.x + x * m.y);
        gQ += (double)(m.z + 2.f * x * m.w + x * x * p2);
        float2 a = desc[cix];
        x = a.x + a.y * x;
    }
#pragma unroll
    for (int off = 32; off > 0; off >>= 1) {
        gS += __shfl_down(gS, off);
        gQ += __shfl_down(gQ, off);
    }
    __shared__ double Sa[16], Sb[16];
    if (lane == 0) { Sa[wv] = gS; Sb[wv] = gQ; }
    __syncthreads();
    if (t == 0) {
        double S = 0.0, Q = 0.0;
        for (int w = 0; w < 16; ++w) { S += Sa[w]; Q += Sb[w]; }
        double mean = S / (double)T;
        double var = Q / (double)T - mean * mean;
        double sd = sqrt(var > 0.0 ? var : 0.0);
        meanstd[0] = make_float2((float)mean, (float)(1.0 / (sd + (double)EPS_F)));
    }
}

// Pass 3: read fp16 delta + mask (cache-hot), rescan, apply carry, normalize, write out.
__global__ __launch_bounds__(NT) void k_apply(const __half* __restrict__ dh,
                                              const unsigned long long* __restrict__ dmask,
                                              const float* __restrict__ carry,
                                              const float2* __restrict__ meanstd,
                                              float* __restrict__ out) {
    const int tid = threadIdx.x, lane = tid & 63, wv = tid >> 6;
    const int ch = blockIdx.x * 4 + wv;
    const int base = ch * CHUNK;
    const int o0 = base + lane * PL, o1 = base + TILE + lane * PL;

    float d0[8], d1[8];
    H8 u0, u1;
    u0.f4 = *(const float4*)(dh + o0);
    u1.f4 = *(const float4*)(dh + o1);
#pragma unroll
    for (int i = 0; i < 8; ++i) { d0[i] = __half2float(u0.h[i]); d1[i] = __half2float(u1.h[i]); }

    const unsigned long long* mp = dmask + (size_t)ch * 16;
    float c0[8], c1[8];
#pragma unroll
    for (int i = 0; i < 8; ++i) {
        c0[i] = GL_F * (1.f - (float)((mp[i] >> lane) & 1ull));
        c1[i] = GL_F * (1.f - (float)((mp[8 + i] >> lane) & 1ull));
    }
    const float2 ms = meanstd[0];
    const float cy = carry[ch];

    float sD1, sC1, S1D1, S1C1;
    scan8(d1, c1, lane, sD1, sC1, S1D1, S1C1);
    const float T1D = __shfl(sD1, 0), T1C = __shfl(sC1, 0);
    float sD0, sC0, S1D0, S1C0;
    scan8(d0, c0, lane, sD0, sC0, S1D0, S1C0);

    float o[8];
    float x = S1D1 + S1C1 * cy;                   // tile1: entry = cy at chunk right edge
#pragma unroll
    for (int i = 7; i >= 0; --i) { x = d1[i] + c1[i] * x; o[i] = (x - ms.x) * ms.y; }
    *(float4*)(out + o1)     = make_float4(o[0], o[1], o[2], o[3]);
    *(float4*)(out + o1 + 4) = make_float4(o[4], o[5], o[6], o[7]);
    const float x0e = T1D + T1C * cy;             // tile0: entry = A_tile1(cy)
    x = S1D0 + S1C0 * x0e;
#pragma unroll
    for (int i = 7; i >= 0; --i) { x = d0[i] + c0[i] * x; o[i] = (x - ms.x) * ms.y; }
    *(float4*)(out + o0)     = make_float4(o[0], o[1], o[2], o[3]);
    *(float4*)(out + o0 + 4) = make_float4(o[4], o[5], o[6], o[7]);
}

extern "C" void kernel_launch(void* const* d_in, const int* in_sizes, int n_in,
                              void* d_out, int out_size, void* d_ws, size_t ws_size,
                              hipStream_t stream) {
    const float* rewards = (const float*)d_in[0];
    const float* v_pred  = (const float*)d_in[1];
    const int*   dones   = (const int*)d_in[2];
    float* out = (float*)d_out;
    const long long T = in_sizes[0];          // 16777216
    const int nchunk = (int)(T / CHUNK);      // 16384

    // workspace layout (ws_size >= 36 MB proven in R6)
    char* ws = (char*)d_ws;
    float4* mom4 = (float4*)ws;                                       // 256 KB
    float2* desc = (float2*)(ws + (size_t)nchunk * 16);               // 128 KB
    float*  mom1 = (float*)(ws + (size_t)nchunk * 24);                // 64 KB
    float*  carry = (float*)(ws + (size_t)nchunk * 28);               // 64 KB
    float2* meanstd = (float2*)(ws + (size_t)nchunk * 32);            // 16 B
    unsigned long long* dmask =
        (unsigned long long*)(ws + (size_t)nchunk * 32 + 16);         // 2 MB
    __half* dh = (__half*)(ws + 4ull * 1024 * 1024);                  // 32 MB @ 4 MB

    hipLaunchKernelGGL(k_desc, dim3(nchunk / 4), dim3(NT), 0, stream,
                       rewards, v_pred, dones, desc, mom4, mom1, dmask, dh);
    hipLaunchKernelGGL(k_scan, dim3(1), dim3(K2T), 0, stream,
                       desc, mom4, mom1, carry, meanstd, nchunk, T);
    hipLaunchKernelGGL(k_apply, dim3(nchunk / 4), dim3(NT), 0, stream,
                       dh, dmask, carry, meanstd, out);
}